// Round 3
// baseline (336.120 us; speedup 1.0000x reference)
//
#include <hip/hip_runtime.h>

// SparsePropMaxPool: map_h[b,h,s,e] = max(x[b,h,s..e]) at "active" (s,e)
// positions, 0 elsewhere; map_mask[b,0,s,e] = active ? 1 : 0.
//
// Active predicate (d = e - s >= 0), derived from NUM_SCALE_LAYERS=[16,8,8]:
//   scale 0: d in [0,15], any s
//   scale 1: d in {17,19,...,31} (odd), s even
//   scale 2: d in {35,39,...,63} (d%4==3), s%4==0
//
// B=32, H=512, N=64 fixed by the reference setup.
//
// R3 change: HBM channel decorrelation. The old suffix-max recurrence forced
// all rows machine-wide to write offset s*256B within their 16KB plane in
// lockstep (descending s) -> at any instant only a tiny subset of HBM
// channels served all writes (row stride 16KB is a power of 2) -> ~3 TB/s
// effective vs 6.3 achievable. Replace the recurrence with a per-row O(1)
// range-max sparse table in LDS, which frees the s iteration order; visit
// s = (63 - it + 37*row) & 63 so concurrent rows hit all channel offsets.

#define BB 32
#define HH 512
#define NN 64

typedef float f32x4 __attribute__((ext_vector_type(4)));

__device__ __forceinline__ unsigned long long active_mask_for_e(int e) {
    // Bit s set <=> (s, e) is an active position.
    unsigned long long m;
    // band 1: s in [e-15, e]  (d in [0,15])
    if (e >= 15) m = 0xFFFFull << (e - 15);
    else         m = 0xFFFFull >> (15 - e);
    // band 2: d odd in [17,31], s even  => only when e is odd
    if ((e & 1) && e >= 17) {
        int a = e - 31; if (a < 0) a = 0;
        int b = e - 17;
        unsigned long long r = (~0ull >> (63 - b)) & (~0ull << a);
        m |= r & 0x5555555555555555ull;
    }
    // band 3: d%4==3 in [35,63], s%4==0 => only when e%4==3
    if (((e & 3) == 3) && e >= 35) {
        int b = e - 35;
        unsigned long long r = (~0ull >> (63 - b));
        m |= r & 0x1111111111111111ull;
    }
    return m;
}

__global__ __launch_bounds__(256) void sppool_fused_kernel(
        const float* __restrict__ x, float* __restrict__ map_h,
        float* __restrict__ map_mask) {
    // Sparse table: sp[row][k][i] = max(x[row][i .. i+2^k-1]), k=0..6.
    // Stride 68 floats per level: bank contribution 4k mod 32 -> levels land
    // on distinct banks; row base (476 floats) stays 16B-aligned for the
    // float4 level-0 fill.
    __shared__ float sp[16][7][68];

    const int tid  = threadIdx.x;
    const int lrow = tid >> 4;                // 0..15 local row
    const int lcol = tid & 15;
    const int e0   = lcol << 2;               // this thread's 4 e-values
    const size_t rowbase = (size_t)blockIdx.x * 16;

    // ---- load: 16 rows x 64 floats, one float4 per thread (level 0) ----
    const float* xin = x + rowbase * NN;
    const f32x4 xv = ((const f32x4*)xin)[tid];        // row=tid>>4, col=(tid&15)*4
    *(f32x4*)&sp[lrow][0][e0] = xv;
    __syncthreads();

    // ---- build levels 1..6 (each thread: its row, i = lcol, +16, +32, +48)
    #pragma unroll
    for (int k = 1; k <= 6; ++k) {
        const int off = 1 << (k - 1);
        float v[4];
        #pragma unroll
        for (int ii = 0; ii < 4; ++ii) {
            const int i = lcol + ii * 16;
            int p = i + off; if (p > 63) p = 63;      // clamped entries never queried
            v[ii] = fmaxf(sp[lrow][k - 1][i], sp[lrow][k - 1][p]);
        }
        __syncthreads();   // (writes of level k can't race reads of k-1)
        #pragma unroll
        for (int ii = 0; ii < 4; ++ii)
            sp[lrow][k][lcol + ii * 16] = v[ii];
        __syncthreads();
    }

    const unsigned long long am0 = active_mask_for_e(e0 + 0);
    const unsigned long long am1 = active_mask_for_e(e0 + 1);
    const unsigned long long am2 = active_mask_for_e(e0 + 2);
    const unsigned long long am3 = active_mask_for_e(e0 + 3);

    const int grow  = (int)rowbase + lrow;            // global row index
    const int phase = (grow * 37) & 63;               // odd mult: bijective spread
    const float* rowsp = &sp[lrow][0][0];
    float* out = map_h + (size_t)grow * (NN * NN) + e0;

    #pragma unroll 8
    for (int it = 0; it < 64; ++it) {
        const int s = (63 - it + phase) & 63;
        f32x4 v;
        #pragma unroll
        for (int j = 0; j < 4; ++j) {
            const int e = e0 + j;
            int n = e - s + 1; if (n < 1) n = 1;      // d<0 -> masked anyway
            const int k = 31 - __clz(n);
            const float lo = rowsp[k * 68 + s];
            const float hi = rowsp[k * 68 + (e + 1 - (1 << k))];
            const unsigned long long am = (j == 0) ? am0 : (j == 1) ? am1
                                        : (j == 2) ? am2 : am3;
            const float mv = fmaxf(lo, hi);
            v[j] = ((am >> s) & 1ull) ? mv : 0.0f;
        }
        // 16-lane group: 256B contiguous full lines; write-once -> NT
        __builtin_nontemporal_store(
            v, reinterpret_cast<f32x4*>(out + (size_t)s * NN));
    }

    // Fused mask tail: the 64x64 mask plane is identical for every b, so
    // blocks 0..31 each emit one plane (16 KB).
    if (blockIdx.x < BB) {
        f32x4* mout = reinterpret_cast<f32x4*>(
            map_mask + (size_t)blockIdx.x * (NN * NN));
        #pragma unroll
        for (int kk = 0; kk < 4; ++kk) {
            const int idx = kk * 256 + tid;   // 1024 float4 per plane
            const int eg  = (idx & 15) << 2;
            const int s   = idx >> 4;
            f32x4 v;
            v.x = ((active_mask_for_e(eg + 0) >> s) & 1ull) ? 1.0f : 0.0f;
            v.y = ((active_mask_for_e(eg + 1) >> s) & 1ull) ? 1.0f : 0.0f;
            v.z = ((active_mask_for_e(eg + 2) >> s) & 1ull) ? 1.0f : 0.0f;
            v.w = ((active_mask_for_e(eg + 3) >> s) & 1ull) ? 1.0f : 0.0f;
            __builtin_nontemporal_store(v, mout + idx);
        }
    }
}

extern "C" void kernel_launch(void* const* d_in, const int* in_sizes, int n_in,
                              void* d_out, int out_size, void* d_ws, size_t ws_size,
                              hipStream_t stream) {
    const float* x = (const float*)d_in[0];
    float* map_h    = (float*)d_out;
    float* map_mask = (float*)d_out + (size_t)BB * HH * NN * NN;

    // 16384 rows / 16 rows per block; mask fused into blocks 0..31
    sppool_fused_kernel<<<BB * HH / 16, 256, 0, stream>>>(x, map_h, map_mask);
}

// Round 4
// 267.869 us; speedup vs baseline: 1.2548x; 1.2548x over previous
//
#include <hip/hip_runtime.h>

// SparsePropMaxPool: map_h[b,h,s,e] = max(x[b,h,s..e]) at "active" (s,e)
// positions, 0 elsewhere; map_mask[b,0,s,e] = active ? 1 : 0.
//
// Active predicate (d = e - s >= 0), derived from NUM_SCALE_LAYERS=[16,8,8]:
//   scale 0: d in [0,15], any s
//   scale 1: d in {17,19,...,31} (odd), s even
//   scale 2: d in {35,39,...,63} (d%4==3), s%4==0
//
// B=32, H=512, N=64 fixed by the reference setup.
//
// R4 change: per-instruction write contiguity. Previous lane map gave each
// wave 4 rows -> every store instr = 4 x 256B segments at 16KB stride. The
// harness fill (6.5 TB/s on the same buffer) stores 1KB+ contiguous per
// wave instr. Remap: one row per wave, lane l -> s = 4t + (l>>4),
// e-quad = (l&15)*4, so each store instr is 1KB fully contiguous ascending
// (fill-identical). The R3 sparse table (verified) supplies O(1)
// max(x[s..e]) for the lane-varying (s,e).

#define BB 32
#define HH 512
#define NN 64

typedef float f32x4 __attribute__((ext_vector_type(4)));

__device__ __forceinline__ unsigned long long active_mask_for_e(int e) {
    // Bit s set <=> (s, e) is an active position.
    unsigned long long m;
    // band 1: s in [e-15, e]  (d in [0,15])
    if (e >= 15) m = 0xFFFFull << (e - 15);
    else         m = 0xFFFFull >> (15 - e);
    // band 2: d odd in [17,31], s even  => only when e is odd
    if ((e & 1) && e >= 17) {
        int a = e - 31; if (a < 0) a = 0;
        int b = e - 17;
        unsigned long long r = (~0ull >> (63 - b)) & (~0ull << a);
        m |= r & 0x5555555555555555ull;
    }
    // band 3: d%4==3 in [35,63], s%4==0 => only when e%4==3
    if (((e & 3) == 3) && e >= 35) {
        int b = e - 35;
        unsigned long long r = (~0ull >> (63 - b));
        m |= r & 0x1111111111111111ull;
    }
    return m;
}

__global__ __launch_bounds__(256) void sppool_fused_kernel(
        const float* __restrict__ x, float* __restrict__ map_h,
        float* __restrict__ map_mask) {
    // Sparse table: sp[row][k][i] = max(x[row][i .. i+2^k-1]), k=0..6.
    // Stride 68 floats per level: level contribution 4k mod 32 -> distinct
    // banks per level; row base (476 floats) stays 16B-aligned.
    __shared__ float sp[16][7][68];

    const int tid  = threadIdx.x;
    const int lrow = tid >> 4;                // 0..15 (build phase row)
    const int lcol = tid & 15;
    const size_t rowbase = (size_t)blockIdx.x * 16;

    // ---- load: 16 rows x 64 floats, one float4 per thread (level 0) ----
    const float* xin = x + rowbase * NN;
    const f32x4 xv = ((const f32x4*)xin)[tid];        // row=tid>>4, col=(tid&15)*4
    *(f32x4*)&sp[lrow][0][lcol << 2] = xv;
    __syncthreads();

    // ---- build levels 1..6 (each thread: its row, i = lcol, +16, +32, +48)
    #pragma unroll
    for (int k = 1; k <= 6; ++k) {
        const int off = 1 << (k - 1);
        float v[4];
        #pragma unroll
        for (int ii = 0; ii < 4; ++ii) {
            const int i = lcol + ii * 16;
            int p = i + off; if (p > 63) p = 63;      // clamped entries never queried
            v[ii] = fmaxf(sp[lrow][k - 1][i], sp[lrow][k - 1][p]);
        }
        __syncthreads();
        #pragma unroll
        for (int ii = 0; ii < 4; ++ii)
            sp[lrow][k][lcol + ii * 16] = v[ii];
        __syncthreads();
    }

    // ---- main loop: one row per wave; 1KB contiguous per store instr ----
    const int wave = tid >> 6;                // 0..3
    const int lane = tid & 63;
    const int sg   = lane >> 4;               // s sub-line 0..3
    const int e0   = (lane & 15) << 2;        // this lane's 4 e-values

    const unsigned long long am0 = active_mask_for_e(e0 + 0);
    const unsigned long long am1 = active_mask_for_e(e0 + 1);
    const unsigned long long am2 = active_mask_for_e(e0 + 2);
    const unsigned long long am3 = active_mask_for_e(e0 + 3);

    #pragma unroll
    for (int rr = 0; rr < 4; ++rr) {
        const int lr = rr * 4 + wave;         // local row for this wave
        const float* rowsp = &sp[lr][0][0];
        float* outr = map_h + (rowbase + lr) * (size_t)(NN * NN) + e0;

        #pragma unroll 4
        for (int t = 0; t < 16; ++t) {
            const int s = (t << 2) + sg;
            f32x4 v;
            #pragma unroll
            for (int j = 0; j < 4; ++j) {
                const int e = e0 + j;
                int n = e - s + 1; if (n < 1) n = 1;  // d<0 -> masked anyway
                const int k = 31 - __clz(n);
                const float lo = rowsp[k * 68 + s];
                const float hi = rowsp[k * 68 + (e + 1 - (1 << k))];
                const unsigned long long am = (j == 0) ? am0 : (j == 1) ? am1
                                            : (j == 2) ? am2 : am3;
                v[j] = ((am >> s) & 1ull) ? fmaxf(lo, hi) : 0.0f;
            }
            // wave: lanes 0..63 -> bytes [s*256 .. ) = 1KB contiguous run
            __builtin_nontemporal_store(
                v, reinterpret_cast<f32x4*>(outr + (size_t)s * NN));
        }
    }

    // Fused mask tail: the 64x64 mask plane is identical for every b, so
    // blocks 0..31 each emit one plane (16 KB).
    if (blockIdx.x < BB) {
        f32x4* mout = reinterpret_cast<f32x4*>(
            map_mask + (size_t)blockIdx.x * (NN * NN));
        #pragma unroll
        for (int kk = 0; kk < 4; ++kk) {
            const int idx = kk * 256 + tid;   // 1024 float4 per plane
            const int eg  = (idx & 15) << 2;
            const int s   = idx >> 4;
            f32x4 v;
            v.x = ((active_mask_for_e(eg + 0) >> s) & 1ull) ? 1.0f : 0.0f;
            v.y = ((active_mask_for_e(eg + 1) >> s) & 1ull) ? 1.0f : 0.0f;
            v.z = ((active_mask_for_e(eg + 2) >> s) & 1ull) ? 1.0f : 0.0f;
            v.w = ((active_mask_for_e(eg + 3) >> s) & 1ull) ? 1.0f : 0.0f;
            __builtin_nontemporal_store(v, mout + idx);
        }
    }
}

extern "C" void kernel_launch(void* const* d_in, const int* in_sizes, int n_in,
                              void* d_out, int out_size, void* d_ws, size_t ws_size,
                              hipStream_t stream) {
    const float* x = (const float*)d_in[0];
    float* map_h    = (float*)d_out;
    float* map_mask = (float*)d_out + (size_t)BB * HH * NN * NN;

    // 16384 rows / 16 rows per block; mask fused into blocks 0..31
    sppool_fused_kernel<<<BB * HH / 16, 256, 0, stream>>>(x, map_h, map_mask);
}

// Round 6
// 258.111 us; speedup vs baseline: 1.3022x; 1.0378x over previous
//
#include <hip/hip_runtime.h>

// SparsePropMaxPool: map_h[b,h,s,e] = max(x[b,h,s..e]) at "active" (s,e)
// positions, 0 elsewhere; map_mask[b,0,s,e] = active ? 1 : 0.
//
// Active predicate (d = e - s >= 0), derived from NUM_SCALE_LAYERS=[16,8,8]:
//   scale 0: d in [0,15], any s
//   scale 1: d in {17,19,...,31} (odd), s even
//   scale 2: d in {35,39,...,63} (d%4==3), s%4==0
//
// B=32, H=512, N=64 fixed by the reference setup.
//
// R6 = R5 resubmitted (container infra failure, kernel never ran).
// R5 change: store-stream concurrency. Address-pattern theories are dead
// (R2 NT, R3 phase-decorrelation, R4 1KB-contiguous all neutral at ~3 TB/s
// effective). Remaining delta vs the 6.4 TB/s harness fill: wave count.
// Old: 1024 blocks = 16 waves/CU with block-wide barriers. New: one row per
// wave, 4096 blocks, barrier-free (per-wave shfl-built sparse table in a
// private LDS slice), __launch_bounds__(256,8) -> 32 waves/CU, 2x the
// independent store streams. Stores plain (NT measured slightly negative).

#define BB 32
#define HH 512
#define NN 64

typedef float f32x4 __attribute__((ext_vector_type(4)));

__device__ __forceinline__ unsigned long long active_mask_for_e(int e) {
    // Bit s set <=> (s, e) is an active position.
    unsigned long long m;
    // band 1: s in [e-15, e]  (d in [0,15])
    if (e >= 15) m = 0xFFFFull << (e - 15);
    else         m = 0xFFFFull >> (15 - e);
    // band 2: d odd in [17,31], s even  => only when e is odd
    if ((e & 1) && e >= 17) {
        int a = e - 31; if (a < 0) a = 0;
        int b = e - 17;
        unsigned long long r = (~0ull >> (63 - b)) & (~0ull << a);
        m |= r & 0x5555555555555555ull;
    }
    // band 3: d%4==3 in [35,63], s%4==0 => only when e%4==3
    if (((e & 3) == 3) && e >= 35) {
        int b = e - 35;
        unsigned long long r = (~0ull >> (63 - b));
        m |= r & 0x1111111111111111ull;
    }
    return m;
}

__global__ __launch_bounds__(256, 8) void sppool_fused_kernel(
        const float* __restrict__ x, float* __restrict__ map_h,
        float* __restrict__ map_mask) {
    // Per-wave private sparse table: sp[wave][k][i] = max(x[row][i..i+2^k-1]).
    // Level stride 68 floats: level bank contribution 4k mod 32 -> spread.
    // 4 x 7 x 68 x 4B = 7616 B per block.
    __shared__ float sp[4][7][68];

    const int tid  = threadIdx.x;
    const int wv   = tid >> 6;                 // wave 0..3
    const int lane = tid & 63;
    const int row  = blockIdx.x * 4 + wv;      // one row per wave

    // ---- barrier-free build: register recurrence + private LDS slice ----
    // lane l carries v_k = max(x[row][l .. min(l+2^k-1, 63)])
    float v = x[(size_t)row * NN + lane];       // 256B coalesced per wave
    sp[wv][0][lane] = v;
    #pragma unroll
    for (int k = 1; k <= 6; ++k) {
        int p = lane + (1 << (k - 1)); if (p > 63) p = 63;  // clamp (verified R3/R4)
        const float o = __shfl(v, p);           // ds_bpermute, wave-internal
        v = fmaxf(v, o);
        sp[wv][k][lane] = v;
    }
    // Wave-synchronous LDS: all writes precede reads in this wave's program
    // order; keep the scheduler from hoisting reads above the writes.
    __builtin_amdgcn_wave_barrier();

    // ---- main loop: this wave streams its row, 1KB contiguous per instr ---
    const int sg = lane >> 4;                  // s sub-line 0..3
    const int e0 = (lane & 15) << 2;           // this lane's 4 e-values

    const unsigned long long am0 = active_mask_for_e(e0 + 0);
    const unsigned long long am1 = active_mask_for_e(e0 + 1);
    const unsigned long long am2 = active_mask_for_e(e0 + 2);
    const unsigned long long am3 = active_mask_for_e(e0 + 3);

    const float* rowsp = &sp[wv][0][0];
    float* outr = map_h + (size_t)row * (NN * NN) + e0;

    #pragma unroll 4
    for (int t = 0; t < 16; ++t) {
        const int s = (t << 2) + sg;
        f32x4 o;
        #pragma unroll
        for (int j = 0; j < 4; ++j) {
            const int e = e0 + j;
            int n = e - s + 1; if (n < 1) n = 1;   // d<0 -> masked anyway
            const int k = 31 - __clz(n);
            const float lo = rowsp[k * 68 + s];
            const float hi = rowsp[k * 68 + (e + 1 - (1 << k))];
            const unsigned long long am = (j == 0) ? am0 : (j == 1) ? am1
                                        : (j == 2) ? am2 : am3;
            o[j] = ((am >> s) & 1ull) ? fmaxf(lo, hi) : 0.0f;
        }
        // wave: lanes 0..63 cover bytes [4t*256 .. 4t*256+1024) contiguous
        *reinterpret_cast<f32x4*>(outr + (size_t)s * NN) = o;
    }

    // Fused mask tail: the 64x64 mask plane is identical for every b, so
    // blocks 0..31 each emit one plane (16 KB).
    if (blockIdx.x < BB) {
        f32x4* mout = reinterpret_cast<f32x4*>(
            map_mask + (size_t)blockIdx.x * (NN * NN));
        #pragma unroll
        for (int kk = 0; kk < 4; ++kk) {
            const int idx = kk * 256 + tid;    // 1024 float4 per plane
            const int eg  = (idx & 15) << 2;
            const int s   = idx >> 4;
            f32x4 mv;
            mv.x = ((active_mask_for_e(eg + 0) >> s) & 1ull) ? 1.0f : 0.0f;
            mv.y = ((active_mask_for_e(eg + 1) >> s) & 1ull) ? 1.0f : 0.0f;
            mv.z = ((active_mask_for_e(eg + 2) >> s) & 1ull) ? 1.0f : 0.0f;
            mv.w = ((active_mask_for_e(eg + 3) >> s) & 1ull) ? 1.0f : 0.0f;
            mout[idx] = mv;
        }
    }
}

extern "C" void kernel_launch(void* const* d_in, const int* in_sizes, int n_in,
                              void* d_out, int out_size, void* d_ws, size_t ws_size,
                              hipStream_t stream) {
    const float* x = (const float*)d_in[0];
    float* map_h    = (float*)d_out;
    float* map_mask = (float*)d_out + (size_t)BB * HH * NN * NN;

    // 16384 rows, one per wave: 4096 blocks x 4 waves; mask fused in blocks 0..31
    sppool_fused_kernel<<<BB * HH / 4, 256, 0, stream>>>(x, map_h, map_mask);
}